// Round 4
// baseline (578.205 us; speedup 1.0000x reference)
//
#include <hip/hip_runtime.h>

// Problem constants (fixed by setup_inputs)
#define B_ 8
#define T_ 2048
#define C_ 1024
#define H_ 4096
#define E_ 8
#define S_ (2 * T_)          // slots per batch row (K=2)
#define CAP 320              // int(T/E * 1.25)
#define ME 2560              // rows per expert = B_*CAP (10 x 256)
#define NROWS (E_ * ME)      // 20480 bucket rows

typedef __attribute__((ext_vector_type(8))) short short8;
typedef __attribute__((ext_vector_type(4))) float f32x4;

__device__ __forceinline__ unsigned short f2bf(float f) {
  unsigned u = __float_as_uint(f);
  unsigned r = 0x7FFFu + ((u >> 16) & 1u);   // RNE, no NaN in this data
  return (unsigned short)((u + r) >> 16);
}
__device__ __forceinline__ float bf2f(unsigned short u) {
  return __uint_as_float(((unsigned)u) << 16);
}

__device__ __forceinline__ void gload_lds16(const void* g, void* l) {
  __builtin_amdgcn_global_load_lds(
      (const __attribute__((address_space(1))) unsigned int*)g,
      (__attribute__((address_space(3))) unsigned int*)l, 16, 0, 0);
}

// ---------------- weight transpose+convert ----------------
// in: [R][Cc] fp32 (expert blockIdx.z) -> out: [Cc][R] bf16
__global__ void cvt_transpose(const float* __restrict__ in,
                              unsigned short* __restrict__ out, int R, int Cc) {
  __shared__ float t[64][65];
  const int tid = threadIdx.x;
  const long eoff = (long)blockIdx.z * R * Cc;
  const int r0 = blockIdx.x * 64, c0 = blockIdx.y * 64;
#pragma unroll
  for (int it = 0; it < 4; ++it) {
    int r = it * 16 + (tid >> 4);
    int c = (tid & 15) * 4;
    float4 v = *(const float4*)(in + eoff + (long)(r0 + r) * Cc + c0 + c);
    t[r][c] = v.x; t[r][c + 1] = v.y; t[r][c + 2] = v.z; t[r][c + 3] = v.w;
  }
  __syncthreads();
#pragma unroll
  for (int it = 0; it < 4; ++it) {
    int oc = it * 16 + (tid >> 4);   // column index (output row c0+oc)
    int orr = (tid & 15) * 4;        // original rows r0+orr..+3 (output cols)
    union { unsigned short u[4]; unsigned long long ll; } o;
    o.u[0] = f2bf(t[orr + 0][oc]); o.u[1] = f2bf(t[orr + 1][oc]);
    o.u[2] = f2bf(t[orr + 2][oc]); o.u[3] = f2bf(t[orr + 3][oc]);
    *(unsigned long long*)(out + eoff + (long)(c0 + oc) * R + r0 + orr) = o.ll;
  }
}

// ---------------- fused router + x->bf16 convert: one wave per token --------
__global__ void router_cvt(const float* __restrict__ x, const float* __restrict__ Wr,
                           int* __restrict__ es, float* __restrict__ ps,
                           unsigned short* __restrict__ x_bf) {
  const int token = blockIdx.x * 4 + (threadIdx.x >> 6);
  const int lane = threadIdx.x & 63;
  const float* xr = x + (long)token * C_;
  float acc[8] = {0, 0, 0, 0, 0, 0, 0, 0};
#pragma unroll
  for (int j = 0; j < 4; ++j) {
    int c = j * 256 + lane * 4;
    float4 xv = *(const float4*)(xr + c);
    union { unsigned short u[4]; unsigned long long ll; } o;
    o.u[0] = f2bf(xv.x); o.u[1] = f2bf(xv.y); o.u[2] = f2bf(xv.z); o.u[3] = f2bf(xv.w);
    *(unsigned long long*)(x_bf + (long)token * C_ + c) = o.ll;
    const float xe[4] = {xv.x, xv.y, xv.z, xv.w};
#pragma unroll
    for (int i = 0; i < 4; ++i) {
      const float4* wr = (const float4*)(Wr + (long)(c + i) * 8);
      float4 w0 = wr[0], w1 = wr[1];
      float v = xe[i];
      acc[0] += v * w0.x; acc[1] += v * w0.y; acc[2] += v * w0.z; acc[3] += v * w0.w;
      acc[4] += v * w1.x; acc[5] += v * w1.y; acc[6] += v * w1.z; acc[7] += v * w1.w;
    }
  }
#pragma unroll
  for (int off = 32; off >= 1; off >>= 1)
#pragma unroll
    for (int e = 0; e < 8; ++e) acc[e] += __shfl_xor(acc[e], off);
  float mx = acc[0];
#pragma unroll
  for (int e = 1; e < 8; ++e) mx = fmaxf(mx, acc[e]);
  float pr[8], se = 0.f;
#pragma unroll
  for (int e = 0; e < 8; ++e) { pr[e] = expf(acc[e] - mx); se += pr[e]; }
  float inv = 1.f / se;
  // top-2 on probs, jax tie-break: lower index wins on equality (strict >)
  int e0 = 0; float v0 = pr[0];
#pragma unroll
  for (int e = 1; e < 8; ++e) if (pr[e] > v0) { v0 = pr[e]; e0 = e; }
  int e1 = -1; float v1 = -1.f;
#pragma unroll
  for (int e = 0; e < 8; ++e) if (e != e0 && pr[e] > v1) { v1 = pr[e]; e1 = e; }
  if (lane == 0) {
    es[2 * token] = e0;     ps[2 * token] = v0 * inv;
    es[2 * token + 1] = e1; ps[2 * token + 1] = v1 * inv;
  }
}

// ---------------- positions: sequential scan per batch row ----------------
// tsrc[e*ME + b*CAP + pos] = global x row (b*T + t); -1 where bucket empty.
__global__ void positions(const int* __restrict__ es, int* __restrict__ pos,
                          int* __restrict__ tsrc) {
  const int b = blockIdx.x;
  const int lane = threadIdx.x;  // 64 threads
  int cnt[8] = {0, 0, 0, 0, 0, 0, 0, 0};
  unsigned long long below = (1ULL << lane) - 1ULL;
  int e_next = es[(long)b * S_ + lane];
  for (int chunk = 0; chunk < S_ / 64; ++chunk) {
    int e = e_next;
    if (chunk + 1 < S_ / 64) e_next = es[(long)b * S_ + (chunk + 1) * 64 + lane];
    int myPos = 0;
#pragma unroll
    for (int ei = 0; ei < 8; ++ei) {
      unsigned long long m = __ballot(e == ei);
      if (e == ei) myPos = cnt[ei] + __popcll(m & below);
      cnt[ei] += __popcll(m);
    }
    int s = chunk * 64 + lane;
    pos[(long)b * S_ + s] = myPos;
    if (myPos < CAP)
      tsrc[(long)e * ME + b * CAP + myPos] = b * T_ + (s >> 1);
  }
}

// ---------------- 256x256 pipelined grouped GEMM (T2+T3+T4+T5) -------------
// 8 waves (2M x 4N), per-wave 128x64 out, BK=64, LDS 128KB double-buffered.
// Per K-tile: 4 phases {ds_read quadrant (+B at ph0, reg-resident), stage one
// half-tile of tile t+1 into buf[cur^1], lgkmcnt(0), setprio, 16 MFMA}.
// Intra-tile: reads buf[cur] only, writes buf[cur^1] only -> no hazard, no
// intra-tile barrier. One __syncthreads()/tile; its vmcnt(0) drain is cheap
// because the 8 loads were issued 1-4 phases (~600 cyc of MFMA) earlier.
// Split-K: KS slices of Kslice, ks-th block writes outp[ks*NROWS...], bias
// added only on ks==0.
template <bool GATHER, bool RELU>
__global__ __launch_bounds__(512, 2) void moe_gemm256(
    const unsigned short* __restrict__ A, const unsigned short* __restrict__ BT,
    const float* __restrict__ bias, const int* __restrict__ tsrc,
    unsigned short* __restrict__ outp, const int Kfull, const int Kslice,
    const int NT, const int KS) {
  constexpr int BK = 64;
  constexpr int MT = ME / 256;  // 10
  __shared__ unsigned short As[2][256 * BK];  // 64 KB
  __shared__ unsigned short Bs[2][256 * BK];  // 64 KB
  const int tid = threadIdx.x, lane = tid & 63, w = tid >> 6;
  const int wr = w >> 2, wc = w & 3;
  const int N = NT * 256;

  // grid: E*KS*NT*MT (mt fastest), XCD-chunked (grid always %8==0)
  const int nwg = E_ * KS * NT * MT;
  const int chunk = nwg >> 3;
  const int swz = (blockIdx.x & 7) * chunk + (blockIdx.x >> 3);
  const int mt = swz % MT;
  int rem = swz / MT;
  const int nt = rem % NT; rem /= NT;
  const int ks = rem % KS;
  const int e = rem / KS;
  const int n0 = nt * 256;
  const long ksoff = (long)ks * Kslice;

  // staging source pointers: idx = half*2 + issue; row = half*128+i*64+w*8+(lane>>3)
  // source slot pre-swizzled (p ^ (row&7)) so linear gload_lds dest + swizzled
  // ds_read are the same involution (rule #21).
  const unsigned short* aPtr[4];
#pragma unroll
  for (int hh = 0; hh < 2; ++hh)
#pragma unroll
    for (int i = 0; i < 2; ++i) {
      int r = hh * 128 + i * 64 + w * 8 + (lane >> 3);
      int p = lane & 7;
      long rowbase;
      if constexpr (GATHER) {
        int xrow = tsrc[(long)e * ME + mt * 256 + r];
        if (xrow < 0) xrow = 0;  // empty bucket row: garbage, never gathered back
        rowbase = (long)xrow * Kfull;
      } else {
        rowbase = ((long)e * ME + mt * 256 + r) * (long)Kfull;
      }
      aPtr[hh * 2 + i] = A + rowbase + ksoff + ((p ^ (r & 7)) << 3);
    }
  const unsigned short* bPtr[4];
#pragma unroll
  for (int hh = 0; hh < 2; ++hh)
#pragma unroll
    for (int i = 0; i < 2; ++i) {
      int r = hh * 128 + i * 64 + w * 8 + (lane >> 3);
      int p = lane & 7;
      bPtr[hh * 2 + i] =
          BT + ((long)e * N + n0 + r) * (long)Kfull + ksoff + ((p ^ (r & 7)) << 3);
    }

  f32x4 acc[8][4];
#pragma unroll
  for (int m = 0; m < 8; ++m)
#pragma unroll
    for (int n = 0; n < 4; ++n) acc[m][n] = (f32x4){0.f, 0.f, 0.f, 0.f};

  const int l15 = lane & 15, l4 = lane >> 4;

  // prologue: stage tile 0 fully into buf 0; __syncthreads drains vmcnt.
#pragma unroll
  for (int hh = 0; hh < 2; ++hh)
#pragma unroll
    for (int i = 0; i < 2; ++i) {
      gload_lds16(aPtr[hh * 2 + i], &As[0][(hh * 128 + i * 64 + w * 8) * BK]);
      gload_lds16(bPtr[hh * 2 + i], &Bs[0][(hh * 128 + i * 64 + w * 8) * BK]);
    }
  __syncthreads();

  const int nkt = Kslice / BK;
  int cur = 0;
  for (int kt = 0; kt < nkt; ++kt) {
    const bool pf = (kt + 1 < nkt);
    const long koff = (long)(kt + 1) * BK;
    short8 bfr[4][2];
#pragma unroll
    for (int q = 0; q < 4; ++q) {
      if (q == 0) {  // B-frags for the whole tile, held in regs
#pragma unroll
        for (int n = 0; n < 4; ++n)
#pragma unroll
          for (int s = 0; s < 2; ++s) {
            int r = wc * 64 + n * 16 + l15;
            int slot = (s * 4 + l4) ^ (r & 7);
            bfr[n][s] = *(const short8*)&Bs[cur][r * BK + slot * 8];
          }
      }
      short8 af[2][2];
#pragma unroll
      for (int mi = 0; mi < 2; ++mi)
#pragma unroll
        for (int s = 0; s < 2; ++s) {
          int r = wr * 128 + (q * 2 + mi) * 16 + l15;
          int slot = (s * 4 + l4) ^ (r & 7);
          af[mi][s] = *(const short8*)&As[cur][r * BK + slot * 8];
        }
      if (pf) {  // stage half-tile q of tile kt+1 into the other buffer
        if (q < 2) {
          gload_lds16(aPtr[q * 2 + 0] + koff,
                      &As[cur ^ 1][(q * 128 + 0 + w * 8) * BK]);
          gload_lds16(aPtr[q * 2 + 1] + koff,
                      &As[cur ^ 1][(q * 128 + 64 + w * 8) * BK]);
        } else {
          gload_lds16(bPtr[(q - 2) * 2 + 0] + koff,
                      &Bs[cur ^ 1][((q - 2) * 128 + 0 + w * 8) * BK]);
          gload_lds16(bPtr[(q - 2) * 2 + 1] + koff,
                      &Bs[cur ^ 1][((q - 2) * 128 + 64 + w * 8) * BK]);
        }
      }
      asm volatile("s_waitcnt lgkmcnt(0)" ::: "memory");
      __builtin_amdgcn_sched_barrier(0);
      __builtin_amdgcn_s_setprio(1);
#pragma unroll
      for (int mi = 0; mi < 2; ++mi)
#pragma unroll
        for (int n = 0; n < 4; ++n)
#pragma unroll
          for (int s = 0; s < 2; ++s)
            acc[q * 2 + mi][n] = __builtin_amdgcn_mfma_f32_16x16x32_bf16(
                af[mi][s], bfr[n][s], acc[q * 2 + mi][n], 0, 0, 0);
      __builtin_amdgcn_s_setprio(0);
      __builtin_amdgcn_sched_barrier(0);
    }
    __syncthreads();  // drains this tile's stage loads; next tile reads them
    cur ^= 1;
  }

  // epilogue: C/D layout col=lane&15, row=(lane>>4)*4+j  [m89]
  const long rbase = (long)ks * NROWS + (long)e * ME + mt * 256;
#pragma unroll
  for (int m = 0; m < 8; ++m) {
#pragma unroll
    for (int n = 0; n < 4; ++n) {
      const int trow = wr * 128 + m * 16 + (l4 << 2);
      const int col = n0 + wc * 64 + n * 16 + l15;
      const float bv = (ks == 0) ? bias[(long)e * N + col] : 0.f;
#pragma unroll
      for (int j = 0; j < 4; ++j) {
        float v = acc[m][n][j] + bv;
        if constexpr (RELU) v = fmaxf(v, 0.f);
        outp[(rbase + trow + j) * (long)N + col] = f2bf(v);
      }
    }
  }
}

// ---------------- combine (y = 2 bf16 split-K partials) ----------------
__global__ void combine(const unsigned short* __restrict__ y,
                        const int* __restrict__ es, const float* __restrict__ ps,
                        const int* __restrict__ pos, float* __restrict__ out) {
  const int token = blockIdx.x;  // b*T + t
  const int b = token >> 11;     // T = 2048
  const int s0 = 2 * token, s1 = s0 + 1;
  int e0 = es[s0], e1 = es[s1];
  int q0 = pos[s0], q1 = pos[s1];
  float p0 = ps[s0], p1 = ps[s1];
  const bool k0 = q0 < CAP, k1 = q1 < CAP;
  if (q0 > CAP - 1) q0 = CAP - 1;
  if (q1 > CAP - 1) q1 = CAP - 1;
  const long half = (long)NROWS * C_;
  const unsigned short* r0 = y + ((long)e0 * ME + b * CAP + q0) * C_;
  const unsigned short* r1 = y + ((long)e1 * ME + b * CAP + q1) * C_;
  const int c = threadIdx.x * 4;  // 256 threads x 4 cols
  float4 a = {0.f, 0.f, 0.f, 0.f};
  if (k0) {
    union { unsigned short u[4]; unsigned long long ll; } v, vv;
    v.ll = *(const unsigned long long*)(r0 + c);
    vv.ll = *(const unsigned long long*)(r0 + half + c);
    a.x += p0 * (bf2f(v.u[0]) + bf2f(vv.u[0]));
    a.y += p0 * (bf2f(v.u[1]) + bf2f(vv.u[1]));
    a.z += p0 * (bf2f(v.u[2]) + bf2f(vv.u[2]));
    a.w += p0 * (bf2f(v.u[3]) + bf2f(vv.u[3]));
  }
  if (k1) {
    union { unsigned short u[4]; unsigned long long ll; } v, vv;
    v.ll = *(const unsigned long long*)(r1 + c);
    vv.ll = *(const unsigned long long*)(r1 + half + c);
    a.x += p1 * (bf2f(v.u[0]) + bf2f(vv.u[0]));
    a.y += p1 * (bf2f(v.u[1]) + bf2f(vv.u[1]));
    a.z += p1 * (bf2f(v.u[2]) + bf2f(vv.u[2]));
    a.w += p1 * (bf2f(v.u[3]) + bf2f(vv.u[3]));
  }
  *(float4*)(out + (long)token * C_ + c) = a;
}

// ---------------- launch ----------------
extern "C" void kernel_launch(void* const* d_in, const int* in_sizes, int n_in,
                              void* d_out, int out_size, void* d_ws, size_t ws_size,
                              hipStream_t stream) {
  const float* x = (const float*)d_in[0];
  const float* Wr = (const float*)d_in[1];
  const float* W1 = (const float*)d_in[2];
  const float* b1 = (const float*)d_in[3];
  const float* W2 = (const float*)d_in[4];
  const float* b2 = (const float*)d_in[5];
  float* out = (float*)d_out;
  char* ws = (char*)d_ws;
  // workspace layout (~420 MB)
  unsigned short* x_bf = (unsigned short*)(ws + 0L);          // 33,554,432
  unsigned short* W1T = (unsigned short*)(ws + 33554432L);    // 67,108,864  [E][H][C]
  unsigned short* W2T = (unsigned short*)(ws + 100663296L);   // 67,108,864  [E][C][H]
  unsigned short* h = (unsigned short*)(ws + 167772160L);     // 167,772,160 [NROWS][H]
  unsigned short* y = (unsigned short*)(ws + 335544320L);     // 83,886,080  [2][NROWS][C] bf16
  int* es = (int*)(ws + 419430400L);                          // 131,072
  float* ps = (float*)(ws + 419561472L);                      // 131,072
  int* pos = (int*)(ws + 419692544L);                         // 131,072
  int* tsrc = (int*)(ws + 419823616L);                        // 81,920

  cvt_transpose<<<dim3(16, 64, 8), 256, 0, stream>>>(W1, W1T, C_, H_);
  cvt_transpose<<<dim3(64, 16, 8), 256, 0, stream>>>(W2, W2T, H_, C_);
  router_cvt<<<4096, 256, 0, stream>>>(x, Wr, es, ps, x_bf);
  hipMemsetAsync(tsrc, 0xFF, NROWS * sizeof(int), stream);
  positions<<<8, 64, 0, stream>>>(es, pos, tsrc);
  // GEMM1: per-expert M=2560 (10 tiles), N=4096 (NT=16), K=1024, no split:
  // grid 8*1*16*10 = 1280 = 5*256 (perfect packing)
  moe_gemm256<true, true><<<1280, 512, 0, stream>>>(x_bf, W1T, b1, tsrc, h,
                                                    C_, C_, 16, 1);
  // GEMM2: N=1024 (NT=4), K=4096 split-K=2 (Kslice=2048): grid 8*2*4*10 = 640
  moe_gemm256<false, false><<<640, 512, 0, stream>>>(h, W2T, b2, nullptr, y,
                                                     H_, H_ / 2, 4, 2);
  combine<<<16384, 256, 0, stream>>>(y, es, ps, pos, out);
}